// Round 1
// baseline (359.573 us; speedup 1.0000x reference)
//
#include <hip/hip_runtime.h>
#include <math.h>

#define BB 32
#define DD 64
#define LL 8192
#define KK 512
#define NN (BB*LL)                 // 262144 rows

#define OUT0_SZ  (BB*DD*LL)        // 16777216
#define LOSS_OFF (OUT0_SZ)         // 16777216
#define PERP_OFF (OUT0_SZ + 1)     // 16777217
#define W_OFF    (OUT0_SZ + 2)     // 16777218
#define IDX_OFF  (W_OFF + KK*DD)   // 16809986

// ws layout: float t[512] | int hist[512] | float loss_acc
// -----------------------------------------------------------------------------
// init: t_k = ||w_k||^2 in numpy-pairwise(unroll-8) fp32 order; zero hist/loss
__global__ void vq_init(const float* __restrict__ w, float* __restrict__ tvec,
                        int* __restrict__ hist, float* __restrict__ lacc) {
#pragma clang fp contract(off)
  int k = blockIdx.x * blockDim.x + threadIdx.x;
  if (k < KK) {
    const float* wr = w + k * DD;
    float r[8];
#pragma unroll
    for (int j = 0; j < 8; j++) { float v = wr[j]; r[j] = v * v; }
#pragma unroll
    for (int blk = 8; blk < 64; blk += 8) {
#pragma unroll
      for (int j = 0; j < 8; j++) { float v = wr[blk + j]; float a = v * v; r[j] = r[j] + a; }
    }
    tvec[k] = ((r[0] + r[1]) + (r[2] + r[3])) + ((r[4] + r[5]) + (r[6] + r[7]));
    hist[k] = 0;
  }
  if (k == 0 && blockIdx.x == 0) *lacc = 0.0f;
}

// -----------------------------------------------------------------------------
// main: 256 threads, 2 rows/thread, 512 rows/block, 512 blocks.
__launch_bounds__(256, 2)
__global__ void vq_main(const float* __restrict__ x, const float* __restrict__ w,
                        const float* __restrict__ tvec, int* __restrict__ hist,
                        float* __restrict__ lacc, float* __restrict__ dout) {
#pragma clang fp contract(off)
  __shared__ float4 wt[64 * 16];    // 64 codes x 64 floats = 16 KB
  __shared__ float  tt[64];
  __shared__ unsigned char flags[KK];

  const int tid = threadIdx.x;
  for (int e = tid; e < KK; e += 256) flags[e] = 0;   // covered by first barrier

  const int n0 = blockIdx.x * 512 + tid;
  const int n1 = n0 + 256;
  const int b0 = n0 >> 13, l0 = n0 & 8191;
  const int b1 = n1 >> 13, l1 = n1 & 8191;
  const float* p0 = x + (size_t)b0 * DD * LL + l0;
  const float* p1 = x + (size_t)b1 * DD * LL + l1;

  float x0[64], x1[64];
#pragma unroll
  for (int i = 0; i < 64; i++) { x0[i] = p0[(size_t)i * LL]; x1[i] = p1[(size_t)i * LL]; }

  // s = ||x||^2, numpy-pairwise order (precision non-critical: uniform shift)
  float s0, s1;
  {
    float r0[8], r1[8];
#pragma unroll
    for (int j = 0; j < 8; j++) { r0[j] = x0[j] * x0[j]; r1[j] = x1[j] * x1[j]; }
#pragma unroll
    for (int blk = 8; blk < 64; blk += 8) {
#pragma unroll
      for (int j = 0; j < 8; j++) {
        float a0 = x0[blk + j] * x0[blk + j]; r0[j] = r0[j] + a0;
        float a1 = x1[blk + j] * x1[blk + j]; r1[j] = r1[j] + a1;
      }
    }
    s0 = ((r0[0] + r0[1]) + (r0[2] + r0[3])) + ((r0[4] + r0[5]) + (r0[6] + r0[7]));
    s1 = ((r1[0] + r1[1]) + (r1[2] + r1[3])) + ((r1[4] + r1[5]) + (r1[6] + r1[7]));
  }

  float dmin0 = INFINITY, dmin1 = INFINITY;
  int   k0 = 0, k1 = 0;
  const float4* w4 = (const float4*)w;

  for (int kc = 0; kc < KK; kc += 64) {
    __syncthreads();
#pragma unroll
    for (int q = 0; q < 4; q++) wt[tid + q * 256] = w4[kc * 16 + tid + q * 256];
    if (tid < 64) tt[tid] = tvec[kc + tid];
    __syncthreads();

    for (int c = 0; c < 64; c++) {
      float g0 = 0.0f, g1 = 0.0f;
#pragma unroll
      for (int i = 0; i < 16; i++) {
        float4 ww = wt[c * 16 + i];
        g0 = fmaf(x0[4*i+0], ww.x, g0); g0 = fmaf(x0[4*i+1], ww.y, g0);
        g0 = fmaf(x0[4*i+2], ww.z, g0); g0 = fmaf(x0[4*i+3], ww.w, g0);
        g1 = fmaf(x1[4*i+0], ww.x, g1); g1 = fmaf(x1[4*i+1], ww.y, g1);
        g1 = fmaf(x1[4*i+2], ww.z, g1); g1 = fmaf(x1[4*i+3], ww.w, g1);
      }
      float tc = tt[c];
      float u0 = s0 + tc;                 // fl32(s + t_k) — matches np broadcast add
      float u1 = s1 + tc;
      float d0 = fmaf(-2.0f, g0, u0);     // fl32(u - 2g), 2g exact
      float d1 = fmaf(-2.0f, g1, u1);
      if (d0 < dmin0) { dmin0 = d0; k0 = kc + c; }   // strict <: first index on tie
      if (d1 < dmin1) { dmin1 = d1; k1 = kc + c; }
    }
  }

  // epilogue: quantized output (transposed back), loss partial, idx, flags
  float ls = 0.0f;
  {
    float* o0 = dout + (size_t)b0 * DD * LL + l0;
    const float4* wr = (const float4*)(w + k0 * DD);
#pragma unroll
    for (int i = 0; i < 16; i++) {
      float4 v = wr[i];
      o0[(size_t)(4*i+0) * LL] = v.x; o0[(size_t)(4*i+1) * LL] = v.y;
      o0[(size_t)(4*i+2) * LL] = v.z; o0[(size_t)(4*i+3) * LL] = v.w;
      float df;
      df = v.x - x0[4*i+0]; ls = fmaf(df, df, ls);
      df = v.y - x0[4*i+1]; ls = fmaf(df, df, ls);
      df = v.z - x0[4*i+2]; ls = fmaf(df, df, ls);
      df = v.w - x0[4*i+3]; ls = fmaf(df, df, ls);
    }
  }
  {
    float* o1 = dout + (size_t)b1 * DD * LL + l1;
    const float4* wr = (const float4*)(w + k1 * DD);
#pragma unroll
    for (int i = 0; i < 16; i++) {
      float4 v = wr[i];
      o1[(size_t)(4*i+0) * LL] = v.x; o1[(size_t)(4*i+1) * LL] = v.y;
      o1[(size_t)(4*i+2) * LL] = v.z; o1[(size_t)(4*i+3) * LL] = v.w;
      float df;
      df = v.x - x1[4*i+0]; ls = fmaf(df, df, ls);
      df = v.y - x1[4*i+1]; ls = fmaf(df, df, ls);
      df = v.z - x1[4*i+2]; ls = fmaf(df, df, ls);
      df = v.w - x1[4*i+3]; ls = fmaf(df, df, ls);
    }
  }
  dout[IDX_OFF + n0] = (float)k0;
  dout[IDX_OFF + n1] = (float)k1;

  // loss: wave reduce then one atomic per wave (threshold is huge; order-insensitive)
#pragma unroll
  for (int o = 32; o > 0; o >>= 1) ls += __shfl_down(ls, o);
  if ((tid & 63) == 0) atomicAdd(lacc, ls);

  // perplexity histogram: LDS filter then <=512 global atomics per block
  flags[k0] = 1; flags[k1] = 1;
  __syncthreads();
  for (int e = tid; e < KK; e += 256)
    if (flags[e]) atomicOr(&hist[e], 1);
}

// -----------------------------------------------------------------------------
// final: perplexity count, loss scalar, weight passthrough
__global__ void vq_final(const float* __restrict__ w, const int* __restrict__ hist,
                         const float* __restrict__ lacc, float* __restrict__ dout) {
  __shared__ int red[512];
  int tid = threadIdx.x;
  red[tid] = (hist[tid] != 0) ? 1 : 0;
  __syncthreads();
  for (int s = 256; s > 0; s >>= 1) {
    if (tid < s) red[tid] += red[tid + s];
    __syncthreads();
  }
  if (tid == 0) {
    dout[PERP_OFF] = (float)red[0];
    float m = *lacc / 16777216.0f;
    dout[LOSS_OFF] = m + 0.1f * m;   // q + 0.1*e with q==e numerically
  }
  // weight passthrough: W_OFF is 8B-aligned only -> float2 copies
  const float2* w2 = (const float2*)w;
  float2* o2 = (float2*)(dout + W_OFF);
  for (int j = tid; j < KK * DD / 2; j += 512) o2[j] = w2[j];
}

extern "C" void kernel_launch(void* const* d_in, const int* in_sizes, int n_in,
                              void* d_out, int out_size, void* d_ws, size_t ws_size,
                              hipStream_t stream) {
  const float* x = (const float*)d_in[0];
  const float* w = (const float*)d_in[1];
  float* dout = (float*)d_out;
  float* tvec = (float*)d_ws;
  int*   hist = (int*)d_ws + 512;
  float* lacc = (float*)d_ws + 1024;

  vq_init<<<2, 256, 0, stream>>>(w, tvec, hist, lacc);
  vq_main<<<NN / 512, 256, 0, stream>>>(x, w, tvec, hist, lacc, dout);
  vq_final<<<1, 512, 0, stream>>>(w, hist, lacc, dout);
}